// Round 2
// baseline (1742.444 us; speedup 1.0000x reference)
//
#include <hip/hip_runtime.h>

#define NN    8192
#define WSZ   256
#define KKEEP 179
#define SCALE 0.044194173824159216f   // 512^-0.5

// ---------------------------------------------------------------------------
// Generic fp32 GEMM: C[M,N] = A[M,K] @ B[K,N] (+ bias[N]). Row-major.
// A has leading dimension lda (>= K). 128x128 block tile, 256 threads,
// 8x8 per-thread tile. BK=16. M%128==0, N%128==0, K%16==0.
// ---------------------------------------------------------------------------
__global__ __launch_bounds__(256) void gemm128(const float* __restrict__ A,
                                               const float* __restrict__ B,
                                               const float* __restrict__ bias,
                                               float* __restrict__ C,
                                               int M, int N, int K, int lda)
{
    __shared__ float As[16 * 132];   // As[kk][r], padded row 132
    __shared__ float Bs[16 * 132];   // Bs[kk][c]

    const int t  = threadIdx.x;
    const int tr = t >> 4;           // 0..15
    const int tc = t & 15;           // 0..15
    const int rowBase = blockIdx.y * 128;
    const int colBase = blockIdx.x * 128;

    float acc[8][8] = {};

    for (int ks = 0; ks < K; ks += 16) {
#pragma unroll
        for (int l = 0; l < 2; ++l) {
            int f = t + l * 256;                 // 0..511
            // A tile: 128 rows x 16 k, transposed into As
            int r  = f >> 2;
            int kg = (f & 3) * 4;
            float4 a4 = *(const float4*)&A[(size_t)(rowBase + r) * lda + ks + kg];
            As[(kg + 0) * 132 + r] = a4.x;
            As[(kg + 1) * 132 + r] = a4.y;
            As[(kg + 2) * 132 + r] = a4.z;
            As[(kg + 3) * 132 + r] = a4.w;
            // B tile: 16 k x 128 cols
            int kk = f >> 5;
            int c  = (f & 31) * 4;
            float4 b4 = *(const float4*)&B[(size_t)(ks + kk) * N + colBase + c];
            *(float4*)&Bs[kk * 132 + c] = b4;
        }
        __syncthreads();

#pragma unroll
        for (int kk = 0; kk < 16; ++kk) {
            float4 a0 = *(const float4*)&As[kk * 132 + 4 * tr];
            float4 a1 = *(const float4*)&As[kk * 132 + 64 + 4 * tr];
            float4 b0 = *(const float4*)&Bs[kk * 132 + 4 * tc];
            float4 b1 = *(const float4*)&Bs[kk * 132 + 64 + 4 * tc];
            float av[8] = {a0.x, a0.y, a0.z, a0.w, a1.x, a1.y, a1.z, a1.w};
            float bv[8] = {b0.x, b0.y, b0.z, b0.w, b1.x, b1.y, b1.z, b1.w};
#pragma unroll
            for (int i = 0; i < 8; ++i)
#pragma unroll
                for (int j = 0; j < 8; ++j)
                    acc[i][j] += av[i] * bv[j];
        }
        __syncthreads();
    }

    float4 bias0 = make_float4(0.f, 0.f, 0.f, 0.f);
    float4 bias1 = bias0;
    if (bias) {
        bias0 = *(const float4*)&bias[colBase + 4 * tc];
        bias1 = *(const float4*)&bias[colBase + 64 + 4 * tc];
    }
#pragma unroll
    for (int i = 0; i < 8; ++i) {
        int row = rowBase + ((i < 4) ? (4 * tr + i) : (64 + 4 * tr + (i - 4)));
        float4 o0, o1;
        o0.x = acc[i][0] + bias0.x; o0.y = acc[i][1] + bias0.y;
        o0.z = acc[i][2] + bias0.z; o0.w = acc[i][3] + bias0.w;
        o1.x = acc[i][4] + bias1.x; o1.y = acc[i][5] + bias1.y;
        o1.z = acc[i][6] + bias1.z; o1.w = acc[i][7] + bias1.w;
        *(float4*)&C[(size_t)row * N + colBase + 4 * tc]      = o0;
        *(float4*)&C[(size_t)row * N + colBase + 64 + 4 * tc] = o1;
    }
}

// ---------------------------------------------------------------------------
// q_mean / k_mean over windows: [b,h,ws,d] = mean_w qkv[b, w*256+i, {0|512}+h*64+dd]
// One thread per (b,h,i,dd). idx = ((b*8+h)*256 + i)*64 + dd.
// ---------------------------------------------------------------------------
__global__ __launch_bounds__(256) void means_kernel(const float* __restrict__ qkv,
                                                    float* __restrict__ q_mean,
                                                    float* __restrict__ k_mean)
{
    int idx = blockIdx.x * 256 + threadIdx.x;    // 0 .. 524287
    int dd = idx & 63;
    int i  = (idx >> 6) & 255;
    int bh = idx >> 14;                          // 0..31
    int b = bh >> 3, h = bh & 7;
    const float* base = qkv + (size_t)b * NN * 1536 + (size_t)h * 64 + dd;
    float qs = 0.f, ks = 0.f;
#pragma unroll
    for (int w = 0; w < 32; ++w) {
        size_t off = (size_t)(w * 256 + i) * 1536;
        qs += base[off];
        ks += base[off + 512];
    }
    q_mean[idx] = qs * 0.03125f;
    k_mean[idx] = ks * 0.03125f;
}

// ---------------------------------------------------------------------------
// global_bias[b,h,m] = mean_g ( (global_param[h,g,:] @ q_mean[b,h,:,:]) . k_mean[b,h,m,:] ) * scale
// One block per (b,h).
// ---------------------------------------------------------------------------
__global__ __launch_bounds__(256) void globalbias_kernel(const float* __restrict__ q_mean,
                                                         const float* __restrict__ k_mean,
                                                         const float* __restrict__ gp,
                                                         float* __restrict__ gbias)
{
    __shared__ float gq[32 * 64];    // gq[g][dd]
    const int bh = blockIdx.x;
    const int h  = bh & 7;
    const int t  = threadIdx.x;

#pragma unroll
    for (int e = 0; e < 8; ++e) {
        int idx = e * 256 + t;       // 0..2047
        int g  = idx >> 6;
        int dd = idx & 63;
        const float* gpr = gp + (size_t)(h * 32 + g) * 256;
        const float* qm  = q_mean + (size_t)bh * 16384 + dd;
        float s = 0.f;
        for (int i = 0; i < 256; ++i) s += gpr[i] * qm[(size_t)i * 64];
        gq[idx] = s;
    }
    __syncthreads();

    const float* km = k_mean + (size_t)bh * 16384 + (size_t)t * 64;
    float4 kr[16];
#pragma unroll
    for (int j = 0; j < 16; ++j) kr[j] = *(const float4*)&km[4 * j];
    float acc = 0.f;
    for (int g = 0; g < 32; ++g) {
        const float* gqr = &gq[g * 64];
        float s = 0.f;
#pragma unroll
        for (int j = 0; j < 16; ++j) {
            float4 q4 = *(const float4*)&gqr[4 * j];
            s += q4.x * kr[j].x + q4.y * kr[j].y + q4.z * kr[j].z + q4.w * kr[j].w;
        }
        acc += s;
    }
    gbias[bh * 256 + t] = acc * SCALE * 0.03125f;   // scale, then mean over g=32
}

// ---------------------------------------------------------------------------
// Fused windowed attention per (b,h,w): S = qk^T*scale + local_bias + gate*gbias,
// exact top-179 row threshold (32-step bisection over monotone-uint fp32),
// softmax, PV. Row-chunks of 64; col-chunks of 64 staged through LDS tiles.
// Per row: 4 threads (sub = t&3) each hold cols {sub+4j} in registers.
// OUTPUT IS WRITTEN IN-PLACE into the q-slice of qkv (cols h*64..h*64+63):
// block (b,h,w) is the sole reader of those addresses, reads q-chunk rc at
// iteration start and overwrites those rows only at iteration end. This
// keeps total workspace under 256 MiB (no separate attn_out buffer).
// LDS = 3 * 64*68*4 = 52224 B -> 3 blocks/CU.
// ---------------------------------------------------------------------------
__global__ __launch_bounds__(256) void attn_kernel(float* __restrict__ qkv,
                                                   const float* __restrict__ local_bias,
                                                   const float* __restrict__ gbias,
                                                   const float* __restrict__ gate)
{
    __shared__ float qT[64 * 68];   // qT[d][r]  (transposed q chunk)
    __shared__ float kT[64 * 68];   // kT[d][m]  (transposed k chunk); reused as v[m][dd] in PV
    __shared__ float st[64 * 68];   // S tile [r][m']

    const int t   = threadIdx.x;
    const int blk = blockIdx.x;            // ((b*8+h)*32 + w)
    const int w   = blk & 31;
    const int bh  = blk >> 5;
    const int h   = bh & 7;
    const int b   = bh >> 3;
    const float gateh = 1.0f / (1.0f + __expf(-gate[h]));

    const size_t tokBase = (size_t)b * NN + (size_t)w * WSZ;
    float* qb = qkv + tokBase * 1536 + h * 64;
    const float* kb = qb + 512;
    const float* vb = qb + 1024;

    const int tr = t >> 4, tc = t & 15;    // S-tile compute mapping (4x4 per thread)
    const int rr = t >> 2, sub = t & 3;    // row-ownership mapping (4 threads / row)

    for (int rc = 0; rc < 4; ++rc) {
        // stage qT (transposed) for rows rc*64 .. rc*64+63
#pragma unroll
        for (int l = 0; l < 4; ++l) {
            int f  = l * 256 + t;
            int r  = f >> 4;
            int dg = (f & 15) * 4;
            float4 v4 = *(const float4*)&qb[(size_t)(rc * 64 + r) * 1536 + dg];
            qT[(dg + 0) * 68 + r] = v4.x;
            qT[(dg + 1) * 68 + r] = v4.y;
            qT[(dg + 2) * 68 + r] = v4.z;
            qT[(dg + 3) * 68 + r] = v4.w;
        }

        float vals[64];
#pragma unroll
        for (int mc = 0; mc < 4; ++mc) {
            __syncthreads();               // prior kT/st readers done; qT visible (mc==0)
#pragma unroll
            for (int l = 0; l < 4; ++l) {
                int f  = l * 256 + t;
                int m  = f >> 4;
                int dg = (f & 15) * 4;
                float4 v4 = *(const float4*)&kb[(size_t)(mc * 64 + m) * 1536 + dg];
                kT[(dg + 0) * 68 + m] = v4.x;
                kT[(dg + 1) * 68 + m] = v4.y;
                kT[(dg + 2) * 68 + m] = v4.z;
                kT[(dg + 3) * 68 + m] = v4.w;
            }
            __syncthreads();

            float acc[4][4] = {};
#pragma unroll 8
            for (int d = 0; d < 64; ++d) {
                float4 q4 = *(const float4*)&qT[d * 68 + 4 * tr];
                float4 k4 = *(const float4*)&kT[d * 68 + 4 * tc];
                float qa[4] = {q4.x, q4.y, q4.z, q4.w};
                float ka[4] = {k4.x, k4.y, k4.z, k4.w};
#pragma unroll
                for (int i = 0; i < 4; ++i)
#pragma unroll
                    for (int j = 0; j < 4; ++j)
                        acc[i][j] += qa[i] * ka[j];
            }
            float4 gb4 = *(const float4*)&gbias[bh * 256 + mc * 64 + 4 * tc];
            float gbl[4] = {gb4.x, gb4.y, gb4.z, gb4.w};
#pragma unroll
            for (int i = 0; i < 4; ++i) {
                int row = rc * 64 + 4 * tr + i;   // row within window (0..255)
                float4 lb4 = *(const float4*)&local_bias[((size_t)h * 256 + row) * 256 + mc * 64 + 4 * tc];
                float4 o;
                o.x = acc[i][0] * SCALE + lb4.x + gateh * gbl[0];
                o.y = acc[i][1] * SCALE + lb4.y + gateh * gbl[1];
                o.z = acc[i][2] * SCALE + lb4.z + gateh * gbl[2];
                o.w = acc[i][3] * SCALE + lb4.w + gateh * gbl[3];
                *(float4*)&st[(4 * tr + i) * 68 + 4 * tc] = o;
            }
            __syncthreads();
            // pull this thread's columns (m = mc*64 + sub + 4j) into registers
#pragma unroll
            for (int j = 0; j < 16; ++j)
                vals[mc * 16 + j] = st[rr * 68 + sub + 4 * j];
        }

        // ---- exact top-KKEEP threshold: bisection over monotone-uint fp32 ----
        unsigned lo, hi;
        {
            unsigned u = __float_as_uint(-1e38f); lo = ~u;               // negative float
            u = __float_as_uint(1e38f);           hi = u | 0x80000000u;  // positive float
        }
        for (int it = 0; it < 32; ++it) {
            unsigned span = hi - lo;
            unsigned mid  = lo + (span >> 1) + (span & 1u);   // ceil midpoint, no overflow
            unsigned mu   = (mid & 0x80000000u) ? (mid ^ 0x80000000u) : ~mid;
            float mf = __uint_as_float(mu);
            int c = 0;
#pragma unroll
            for (int j = 0; j < 64; ++j) c += (vals[j] >= mf) ? 1 : 0;
            c += __shfl_xor(c, 1);
            c += __shfl_xor(c, 2);
            if (c >= KKEEP) lo = mid; else hi = mid - 1;
        }
        float thr;
        {
            unsigned mu = (lo & 0x80000000u) ? (lo ^ 0x80000000u) : ~lo;
            thr = __uint_as_float(mu);
        }

        // ---- masked softmax over kept entries (register-resident) ----
        float rmax = -3e38f;
#pragma unroll
        for (int j = 0; j < 64; ++j) rmax = fmaxf(rmax, (vals[j] >= thr) ? vals[j] : -3e38f);
        rmax = fmaxf(rmax, __shfl_xor(rmax, 1));
        rmax = fmaxf(rmax, __shfl_xor(rmax, 2));
        float rsum = 0.f;
#pragma unroll
        for (int j = 0; j < 64; ++j) {
            float e = (vals[j] >= thr) ? __expf(vals[j] - rmax) : 0.f;
            vals[j] = e;
            rsum += e;
        }
        rsum += __shfl_xor(rsum, 1);
        rsum += __shfl_xor(rsum, 2);
        float rinv = 1.0f / rsum;
#pragma unroll
        for (int j = 0; j < 64; ++j) vals[j] *= rinv;

        // ---- PV: each thread accumulates partial out[rr][0..63] over its m's ----
        float oacc[64];
#pragma unroll
        for (int e = 0; e < 64; ++e) oacc[e] = 0.f;
#pragma unroll
        for (int mc = 0; mc < 4; ++mc) {
            __syncthreads();               // prior kT (v) readers done
#pragma unroll
            for (int l = 0; l < 4; ++l) {  // stage v chunk [m][dd] into kT
                int f  = l * 256 + t;
                int m  = f >> 4;
                int dg = (f & 15) * 4;
                float4 v4 = *(const float4*)&vb[(size_t)(mc * 64 + m) * 1536 + dg];
                *(float4*)&kT[m * 68 + dg] = v4;
            }
            __syncthreads();
#pragma unroll
            for (int j = 0; j < 16; ++j) {
                float p = vals[mc * 16 + j];
                const float* vrow = &kT[(sub + 4 * j) * 68];
#pragma unroll
                for (int dg = 0; dg < 16; ++dg) {
                    float4 v4 = *(const float4*)&vrow[4 * dg];
                    oacc[4 * dg + 0] += p * v4.x;
                    oacc[4 * dg + 1] += p * v4.y;
                    oacc[4 * dg + 2] += p * v4.z;
                    oacc[4 * dg + 3] += p * v4.w;
                }
            }
        }
        // combine the 4 per-row partials (lanes sub=0..3 within the 4-lane group)
#pragma unroll
        for (int e = 0; e < 64; ++e) {
            oacc[e] += __shfl_xor(oacc[e], 1);
            oacc[e] += __shfl_xor(oacc[e], 2);
        }
        // write attention output IN-PLACE over this block's q slice
        float* orow = qb + (size_t)(rc * 64 + rr) * 1536 + sub * 16;
#pragma unroll
        for (int q = 0; q < 4; ++q) {
            if (sub == q) {
#pragma unroll
                for (int i2 = 0; i2 < 4; ++i2) {
                    float4 o;
                    o.x = oacc[q * 16 + 4 * i2 + 0];
                    o.y = oacc[q * 16 + 4 * i2 + 1];
                    o.z = oacc[q * 16 + 4 * i2 + 2];
                    o.w = oacc[q * 16 + 4 * i2 + 3];
                    *(float4*)&orow[4 * i2] = o;
                }
            }
        }
        __syncthreads();   // all writes done before next rc reuses LDS
    }
}

// ---------------------------------------------------------------------------
extern "C" void kernel_launch(void* const* d_in, const int* in_sizes, int n_in,
                              void* d_out, int out_size, void* d_ws, size_t ws_size,
                              hipStream_t stream)
{
    (void)in_sizes; (void)n_in; (void)out_size; (void)ws_size;
    const float* x            = (const float*)d_in[0];
    const float* w_qkv        = (const float*)d_in[1];
    const float* w_out        = (const float*)d_in[2];
    const float* b_out        = (const float*)d_in[3];
    const float* local_bias   = (const float*)d_in[4];
    const float* global_param = (const float*)d_in[5];
    const float* gate         = (const float*)d_in[6];
    float* out = (float*)d_out;
    float* ws  = (float*)d_ws;

    // workspace layout (floats): qkv | q_mean | k_mean | gbias  => ~196 MiB
    float* qkv    = ws;                                   // 32768*1536
    float* q_mean = qkv + (size_t)32768 * 1536;           // 32*256*64
    float* k_mean = q_mean + (size_t)32 * 256 * 64;       // 32*256*64
    float* gb     = k_mean + (size_t)32 * 256 * 64;       // 32*256

    // 1) QKV projection: qkv = x @ w_qkv   (A lda = 512)
    gemm128<<<dim3(12, 256), 256, 0, stream>>>(x, w_qkv, nullptr, qkv, 32768, 1536, 512, 512);
    // 2) window means of q and k
    means_kernel<<<2048, 256, 0, stream>>>(qkv, q_mean, k_mean);
    // 3) global bias per (b,h,m)
    globalbias_kernel<<<32, 256, 0, stream>>>(q_mean, k_mean, global_param, gb);
    // 4) fused windowed attention; output written in-place into q-slice of qkv
    attn_kernel<<<1024, 256, 0, stream>>>(qkv, local_bias, gb, gate);
    // 5) output projection + bias: out = attn(qkv q-slice, lda=1536) @ w_out + b_out
    gemm128<<<dim3(4, 256), 256, 0, stream>>>(qkv, w_out, b_out, out, 32768, 512, 512, 1536);
}

// Round 3
// 1269.442 us; speedup vs baseline: 1.3726x; 1.3726x over previous
//
#include <hip/hip_runtime.h>

#define NN    8192
#define WSZ   256
#define KKEEP 179
#define SCALE 0.044194173824159216f   // 512^-0.5

// ---------------------------------------------------------------------------
// Generic fp32 GEMM: C[M,N] = A[M,K] @ B[K,N] (+ bias[N]). Row-major.
// A has leading dimension lda (>= K). 128x128 block tile, 256 threads,
// 8x8 per-thread tile. BK=16. M%128==0, N%128==0, K%16==0.
// ---------------------------------------------------------------------------
__global__ __launch_bounds__(256) void gemm128(const float* __restrict__ A,
                                               const float* __restrict__ B,
                                               const float* __restrict__ bias,
                                               float* __restrict__ C,
                                               int M, int N, int K, int lda)
{
    __shared__ float As[16 * 132];   // As[kk][r], padded row 132
    __shared__ float Bs[16 * 132];   // Bs[kk][c]

    const int t  = threadIdx.x;
    const int tr = t >> 4;           // 0..15
    const int tc = t & 15;           // 0..15
    const int rowBase = blockIdx.y * 128;
    const int colBase = blockIdx.x * 128;

    float acc[8][8] = {};

    for (int ks = 0; ks < K; ks += 16) {
#pragma unroll
        for (int l = 0; l < 2; ++l) {
            int f = t + l * 256;                 // 0..511
            int r  = f >> 2;
            int kg = (f & 3) * 4;
            float4 a4 = *(const float4*)&A[(size_t)(rowBase + r) * lda + ks + kg];
            As[(kg + 0) * 132 + r] = a4.x;
            As[(kg + 1) * 132 + r] = a4.y;
            As[(kg + 2) * 132 + r] = a4.z;
            As[(kg + 3) * 132 + r] = a4.w;
            int kk = f >> 5;
            int c  = (f & 31) * 4;
            float4 b4 = *(const float4*)&B[(size_t)(ks + kk) * N + colBase + c];
            *(float4*)&Bs[kk * 132 + c] = b4;
        }
        __syncthreads();

#pragma unroll
        for (int kk = 0; kk < 16; ++kk) {
            float4 a0 = *(const float4*)&As[kk * 132 + 4 * tr];
            float4 a1 = *(const float4*)&As[kk * 132 + 64 + 4 * tr];
            float4 b0 = *(const float4*)&Bs[kk * 132 + 4 * tc];
            float4 b1 = *(const float4*)&Bs[kk * 132 + 64 + 4 * tc];
            float av[8] = {a0.x, a0.y, a0.z, a0.w, a1.x, a1.y, a1.z, a1.w};
            float bv[8] = {b0.x, b0.y, b0.z, b0.w, b1.x, b1.y, b1.z, b1.w};
#pragma unroll
            for (int i = 0; i < 8; ++i)
#pragma unroll
                for (int j = 0; j < 8; ++j)
                    acc[i][j] += av[i] * bv[j];
        }
        __syncthreads();
    }

    float4 bias0 = make_float4(0.f, 0.f, 0.f, 0.f);
    float4 bias1 = bias0;
    if (bias) {
        bias0 = *(const float4*)&bias[colBase + 4 * tc];
        bias1 = *(const float4*)&bias[colBase + 64 + 4 * tc];
    }
#pragma unroll
    for (int i = 0; i < 8; ++i) {
        int row = rowBase + ((i < 4) ? (4 * tr + i) : (64 + 4 * tr + (i - 4)));
        float4 o0, o1;
        o0.x = acc[i][0] + bias0.x; o0.y = acc[i][1] + bias0.y;
        o0.z = acc[i][2] + bias0.z; o0.w = acc[i][3] + bias0.w;
        o1.x = acc[i][4] + bias1.x; o1.y = acc[i][5] + bias1.y;
        o1.z = acc[i][6] + bias1.z; o1.w = acc[i][7] + bias1.w;
        *(float4*)&C[(size_t)row * N + colBase + 4 * tc]      = o0;
        *(float4*)&C[(size_t)row * N + colBase + 64 + 4 * tc] = o1;
    }
}

// ---------------------------------------------------------------------------
__global__ __launch_bounds__(256) void means_kernel(const float* __restrict__ qkv,
                                                    float* __restrict__ q_mean,
                                                    float* __restrict__ k_mean)
{
    int idx = blockIdx.x * 256 + threadIdx.x;    // 0 .. 524287
    int dd = idx & 63;
    int i  = (idx >> 6) & 255;
    int bh = idx >> 14;                          // 0..31
    int b = bh >> 3, h = bh & 7;
    const float* base = qkv + (size_t)b * NN * 1536 + (size_t)h * 64 + dd;
    float qs = 0.f, ks = 0.f;
#pragma unroll
    for (int w = 0; w < 32; ++w) {
        size_t off = (size_t)(w * 256 + i) * 1536;
        qs += base[off];
        ks += base[off + 512];
    }
    q_mean[idx] = qs * 0.03125f;
    k_mean[idx] = ks * 0.03125f;
}

// ---------------------------------------------------------------------------
__global__ __launch_bounds__(256) void globalbias_kernel(const float* __restrict__ q_mean,
                                                         const float* __restrict__ k_mean,
                                                         const float* __restrict__ gp,
                                                         float* __restrict__ gbias)
{
    __shared__ float gq[32 * 64];    // gq[g][dd]
    const int bh = blockIdx.x;
    const int h  = bh & 7;
    const int t  = threadIdx.x;

#pragma unroll
    for (int e = 0; e < 8; ++e) {
        int idx = e * 256 + t;       // 0..2047
        int g  = idx >> 6;
        int dd = idx & 63;
        const float* gpr = gp + (size_t)(h * 32 + g) * 256;
        const float* qm  = q_mean + (size_t)bh * 16384 + dd;
        float s = 0.f;
        for (int i = 0; i < 256; ++i) s += gpr[i] * qm[(size_t)i * 64];
        gq[idx] = s;
    }
    __syncthreads();

    const float* km = k_mean + (size_t)bh * 16384 + (size_t)t * 64;
    float4 kr[16];
#pragma unroll
    for (int j = 0; j < 16; ++j) kr[j] = *(const float4*)&km[4 * j];
    float acc = 0.f;
    for (int g = 0; g < 32; ++g) {
        const float* gqr = &gq[g * 64];
        float s = 0.f;
#pragma unroll
        for (int j = 0; j < 16; ++j) {
            float4 q4 = *(const float4*)&gqr[4 * j];
            s += q4.x * kr[j].x + q4.y * kr[j].y + q4.z * kr[j].z + q4.w * kr[j].w;
        }
        acc += s;
    }
    gbias[bh * 256 + t] = acc * SCALE * 0.03125f;
}

// ---------------------------------------------------------------------------
// monotone fp32 <-> uint encoding (order-preserving)
__device__ __forceinline__ unsigned mono_enc(float f) {
    unsigned u = __float_as_uint(f);
    return (u & 0x80000000u) ? ~u : (u | 0x80000000u);
}
__device__ __forceinline__ float mono_dec(unsigned e) {
    return (e & 0x80000000u) ? __uint_as_float(e ^ 0x80000000u)
                             : __uint_as_float(~e);
}

// ---------------------------------------------------------------------------
// Fused windowed attention, one block per (b,h,w,rc): 64 rows x 256 cols.
// Grid 4096 x 256 threads. LDS tiles with column swizzle (col+(d&60))&63 on
// the transposed q/k buffers to kill the 8-way staging-write bank conflicts.
// Top-k: float bisection with exact early-exit (count==K => mask identical to
// reference's >= kth-largest), rare bit-exact bisection fallback.
// PV is a register-tile GEMM (acc2[4][4]) via p written back to LDS
// transposed -- no oacc[64], so VGPR drops and occupancy rises to the LDS cap
// (3 blocks/CU at 52224 B).
// Output written IN-PLACE into this block's own 64 q rows (sole reader).
// ---------------------------------------------------------------------------
__global__ __launch_bounds__(256, 3) void attn_kernel(float* __restrict__ qkv,
                                                      const float* __restrict__ local_bias,
                                                      const float* __restrict__ gbias,
                                                      const float* __restrict__ gate)
{
    __shared__ float qT[64 * 68];   // qT[d][(r+d&60)&63]  swizzled transpose
    __shared__ float kT[64 * 68];   // kT[d][(m+d&60)&63] in S phase; v[m][dd] in PV
    __shared__ float st[64 * 68];   // S tile [r][m']; p^T [m][r] in PV

    const int t   = threadIdx.x;
    const int blk = blockIdx.x;            // (((b*8+h)*32 + w)*4 + rc)
    const int rc  = blk & 3;
    const int w   = (blk >> 2) & 31;
    const int bh  = blk >> 7;
    const int h   = bh & 7;
    const int b   = bh >> 3;
    const float gateh = 1.0f / (1.0f + __expf(-gate[h]));

    const size_t tokBase = (size_t)b * NN + (size_t)w * WSZ;
    float* qb = qkv + tokBase * 1536 + h * 64;
    const float* kb = qb + 512;
    const float* vb = qb + 1024;

    const int tr = t >> 4, tc = t & 15;    // tile compute mapping (4x4 / thread)
    const int rr = t >> 2, sub = t & 3;    // row-ownership mapping (4 thr / row)

    // ---- stage qT (transposed + swizzled) for rows rc*64 .. rc*64+63 ----
#pragma unroll
    for (int l = 0; l < 4; ++l) {
        int f  = l * 256 + t;
        int r  = f >> 4;
        int dg = (f & 15) * 4;
        float4 v4 = *(const float4*)&qb[(size_t)(rc * 64 + r) * 1536 + dg];
        int cs = (r + dg) & 63;            // swizzled column (same for dg..dg+3)
        qT[(dg + 0) * 68 + cs] = v4.x;
        qT[(dg + 1) * 68 + cs] = v4.y;
        qT[(dg + 2) * 68 + cs] = v4.z;
        qT[(dg + 3) * 68 + cs] = v4.w;
    }

    float vals[64];
#pragma unroll
    for (int mc = 0; mc < 4; ++mc) {
        __syncthreads();                   // prior kT/st readers done; qT visible
#pragma unroll
        for (int l = 0; l < 4; ++l) {
            int f  = l * 256 + t;
            int m  = f >> 4;
            int dg = (f & 15) * 4;
            float4 v4 = *(const float4*)&kb[(size_t)(mc * 64 + m) * 1536 + dg];
            int cs = (m + dg) & 63;
            kT[(dg + 0) * 68 + cs] = v4.x;
            kT[(dg + 1) * 68 + cs] = v4.y;
            kT[(dg + 2) * 68 + cs] = v4.z;
            kT[(dg + 3) * 68 + cs] = v4.w;
        }
        __syncthreads();

        float acc[4][4] = {};
#pragma unroll 8
        for (int d = 0; d < 64; ++d) {
            int sw = d & 60;
            float4 q4 = *(const float4*)&qT[d * 68 + ((4 * tr + sw) & 63)];
            float4 k4 = *(const float4*)&kT[d * 68 + ((4 * tc + sw) & 63)];
            float qa[4] = {q4.x, q4.y, q4.z, q4.w};
            float ka[4] = {k4.x, k4.y, k4.z, k4.w};
#pragma unroll
            for (int i = 0; i < 4; ++i)
#pragma unroll
                for (int j = 0; j < 4; ++j)
                    acc[i][j] += qa[i] * ka[j];
        }
        float4 gb4 = *(const float4*)&gbias[bh * 256 + mc * 64 + 4 * tc];
        float gbl[4] = {gb4.x, gb4.y, gb4.z, gb4.w};
#pragma unroll
        for (int i = 0; i < 4; ++i) {
            int row = rc * 64 + 4 * tr + i;    // row within window
            float4 lb4 = *(const float4*)&local_bias[((size_t)h * 256 + row) * 256 + mc * 64 + 4 * tc];
            float4 o;
            o.x = acc[i][0] * SCALE + lb4.x + gateh * gbl[0];
            o.y = acc[i][1] * SCALE + lb4.y + gateh * gbl[1];
            o.z = acc[i][2] * SCALE + lb4.z + gateh * gbl[2];
            o.w = acc[i][3] * SCALE + lb4.w + gateh * gbl[3];
            *(float4*)&st[(4 * tr + i) * 68 + 4 * tc] = o;
        }
        __syncthreads();
#pragma unroll
        for (int j = 0; j < 16; ++j)
            vals[mc * 16 + j] = st[rr * 68 + sub + 4 * j];
    }

    // ---- top-KKEEP threshold ----
    float rmin = vals[0], rmax = vals[0];
#pragma unroll
    for (int j = 1; j < 64; ++j) {
        rmin = fminf(rmin, vals[j]);
        rmax = fmaxf(rmax, vals[j]);
    }
    rmin = fminf(rmin, __shfl_xor(rmin, 1)); rmin = fminf(rmin, __shfl_xor(rmin, 2));
    rmax = fmaxf(rmax, __shfl_xor(rmax, 1)); rmax = fmaxf(rmax, __shfl_xor(rmax, 2));

    float flo = rmin, fhi = rmax;   // invariants: count(>=flo)>=K ; hi shrinks only when count<K
    float thr = 0.f;
    bool  done = false;
    // Phase 1: float bisection with exact early exit.
    for (int it = 0; it < 16; ++it) {
        if (__all(done ? 1 : 0)) break;
        float mf = 0.5f * (flo + fhi);
        int c = 0;
#pragma unroll
        for (int j = 0; j < 64; ++j) c += (vals[j] >= mf) ? 1 : 0;
        c += __shfl_xor(c, 1);
        c += __shfl_xor(c, 2);
        if (!done) {
            if (c == KKEEP)      { thr = mf; done = true; }
            else if (c > KKEEP)  flo = mf;
            else                 fhi = mf;
        }
    }
    // Phase 2 (rare): bit-exact bisection for tie / razor-gap rows.
    if (__any(done ? 0 : 1)) {
        unsigned lo_u = mono_enc(flo), hi_u = mono_enc(fhi);
        for (int it = 0; it < 34; ++it) {
            bool active = (!done) && (lo_u < hi_u);
            if (!__any(active ? 1 : 0)) break;
            unsigned span = hi_u - lo_u;
            unsigned mid  = lo_u + (span >> 1) + (span & 1u);
            float mf = mono_dec(mid);
            int c = 0;
#pragma unroll
            for (int j = 0; j < 64; ++j) c += (vals[j] >= mf) ? 1 : 0;
            c += __shfl_xor(c, 1);
            c += __shfl_xor(c, 2);
            if (active) {
                if (c == KKEEP)      { thr = mf; done = true; }
                else if (c >= KKEEP) lo_u = mid;
                else                 hi_u = mid - 1;
            }
        }
        if (!done) thr = mono_dec(lo_u);
    }

    // ---- masked softmax (register-resident) ----
    float rmx = -3e38f;
#pragma unroll
    for (int j = 0; j < 64; ++j) rmx = fmaxf(rmx, (vals[j] >= thr) ? vals[j] : -3e38f);
    rmx = fmaxf(rmx, __shfl_xor(rmx, 1));
    rmx = fmaxf(rmx, __shfl_xor(rmx, 2));
    float rsum = 0.f;
#pragma unroll
    for (int j = 0; j < 64; ++j) {
        float e = (vals[j] >= thr) ? __expf(vals[j] - rmx) : 0.f;
        vals[j] = e;
        rsum += e;
    }
    rsum += __shfl_xor(rsum, 1);
    rsum += __shfl_xor(rsum, 2);
    float rinv = 1.0f / rsum;
#pragma unroll
    for (int j = 0; j < 64; ++j) vals[j] *= rinv;

    // ---- PV as register-tile GEMM: out[64r x 64d] += p^T-tile * v-tile ----
    float acc2[4][4] = {};
#pragma unroll
    for (int mc = 0; mc < 4; ++mc) {
        __syncthreads();                   // all st/kT readers done
        // p^T chunk into st: st[m][r], m = sub+4j owned by this thread
#pragma unroll
        for (int j = 0; j < 16; ++j)
            st[(sub + 4 * j) * 68 + rr] = vals[mc * 16 + j];
        // v chunk row-major into kT
#pragma unroll
        for (int l = 0; l < 4; ++l) {
            int f  = l * 256 + t;
            int m  = f >> 4;
            int dg = (f & 15) * 4;
            *(float4*)&kT[m * 68 + dg] =
                *(const float4*)&vb[(size_t)(mc * 64 + m) * 1536 + dg];
        }
        __syncthreads();
#pragma unroll 8
        for (int m = 0; m < 64; ++m) {
            float4 p4 = *(const float4*)&st[m * 68 + 4 * tr];
            float4 v4 = *(const float4*)&kT[m * 68 + 4 * tc];
            float pa[4] = {p4.x, p4.y, p4.z, p4.w};
            float va[4] = {v4.x, v4.y, v4.z, v4.w};
#pragma unroll
            for (int i = 0; i < 4; ++i)
#pragma unroll
                for (int j = 0; j < 4; ++j)
                    acc2[i][j] += pa[i] * va[j];
        }
    }

    // ---- write attention output IN-PLACE over this block's q rows ----
#pragma unroll
    for (int i = 0; i < 4; ++i) {
        float4 o;
        o.x = acc2[i][0]; o.y = acc2[i][1]; o.z = acc2[i][2]; o.w = acc2[i][3];
        *(float4*)&qb[(size_t)(rc * 64 + 4 * tr + i) * 1536 + 4 * tc] = o;
    }
}

// ---------------------------------------------------------------------------
extern "C" void kernel_launch(void* const* d_in, const int* in_sizes, int n_in,
                              void* d_out, int out_size, void* d_ws, size_t ws_size,
                              hipStream_t stream)
{
    (void)in_sizes; (void)n_in; (void)out_size; (void)ws_size;
    const float* x            = (const float*)d_in[0];
    const float* w_qkv        = (const float*)d_in[1];
    const float* w_out        = (const float*)d_in[2];
    const float* b_out        = (const float*)d_in[3];
    const float* local_bias   = (const float*)d_in[4];
    const float* global_param = (const float*)d_in[5];
    const float* gate         = (const float*)d_in[6];
    float* out = (float*)d_out;
    float* ws  = (float*)d_ws;

    // workspace layout (floats): qkv | q_mean | k_mean | gbias  => ~196 MiB
    float* qkv    = ws;                                   // 32768*1536
    float* q_mean = qkv + (size_t)32768 * 1536;           // 32*256*64
    float* k_mean = q_mean + (size_t)32 * 256 * 64;       // 32*256*64
    float* gb     = k_mean + (size_t)32 * 256 * 64;       // 32*256

    // 1) QKV projection: qkv = x @ w_qkv   (A lda = 512)
    gemm128<<<dim3(12, 256), 256, 0, stream>>>(x, w_qkv, nullptr, qkv, 32768, 1536, 512, 512);
    // 2) window means of q and k
    means_kernel<<<2048, 256, 0, stream>>>(qkv, q_mean, k_mean);
    // 3) global bias per (b,h,m)
    globalbias_kernel<<<32, 256, 0, stream>>>(q_mean, k_mean, global_param, gb);
    // 4) fused windowed attention; output written in-place into q-slice of qkv
    attn_kernel<<<4096, 256, 0, stream>>>(qkv, local_bias, gb, gate);
    // 5) output projection + bias: out = attn(q-slice of qkv, lda=1536) @ w_out + b_out
    gemm128<<<dim3(4, 256), 256, 0, stream>>>(qkv, w_out, b_out, out, 32768, 512, 512, 1536);
}

// Round 6
// 858.777 us; speedup vs baseline: 2.0290x; 1.4782x over previous
//
#include <hip/hip_runtime.h>

#define NN    8192
#define WSZ   256
#define KKEEP 179
#define SCALE 0.044194173824159216f   // 512^-0.5

typedef __attribute__((ext_vector_type(8))) __bf16 bf16x8;  // MFMA A/B frag (4 VGPRs)
typedef __attribute__((ext_vector_type(4))) short  s16x4;
typedef __attribute__((ext_vector_type(8))) short  s16x8;
typedef __attribute__((ext_vector_type(4))) float  f32x4;

// ---------------------------------------------------------------------------
// Dekker-style 3-way bf16 split: x ~= h + m + l  (repr. error ~2^-24 |x|).
// Bit-twiddled RNE to bf16. Subtractions exact (Sterbenz). Inputs are O(1)
// Gaussians - no inf/NaN edge cases.
// ---------------------------------------------------------------------------
struct Split3 { short h, m, l; };
__device__ __forceinline__ Split3 split3(float x)
{
    unsigned u  = __float_as_uint(x);
    unsigned hb = ((u + 0x7FFFu + ((u >> 16) & 1u)) >> 16) << 16;
    float r = x - __uint_as_float(hb);
    unsigned ur = __float_as_uint(r);
    unsigned mb = ((ur + 0x7FFFu + ((ur >> 16) & 1u)) >> 16) << 16;
    float r2 = r - __uint_as_float(mb);
    unsigned lr = __float_as_uint(r2);
    unsigned lb = (lr + 0x7FFFu + ((lr >> 16) & 1u)) >> 16;
    Split3 s;
    s.h = (short)(hb >> 16);
    s.m = (short)(mb >> 16);
    s.l = (short)(lb & 0xFFFFu);
    return s;
}

// ---------------------------------------------------------------------------
// Pre-split + transpose a weight matrix W[K][N] fp32 -> h/m/l [N][K] bf16.
// ---------------------------------------------------------------------------
__global__ __launch_bounds__(256) void splitw_kernel(const float* __restrict__ W,
                                                     int K, int N,
                                                     short* __restrict__ h,
                                                     short* __restrict__ m,
                                                     short* __restrict__ l)
{
    int idx = blockIdx.x * 256 + threadIdx.x;
    if (idx >= K * N) return;
    int k = idx / N, n = idx - k * N;
    Split3 s = split3(W[idx]);
    size_t o = (size_t)n * K + k;
    h[o] = s.h; m[o] = s.m; l[o] = s.l;
}

// ---------------------------------------------------------------------------
// MFMA GEMM: C[M,N] = A[M,K=512] @ B[K,N] (+bias), A fp32 (lda), B given as
// three pre-split/pre-transposed bf16 limb matrices BT*[N][512].
// A split 3-way in-kernel during LDS staging. cols < qk_cols -> 6 limb
// products (fp32-accurate scores); else 3 products (v / out-proj).
// 128x128 tile, 256 thr = 4 waves (2x2), each wave 4x4 of 16x16x32 MFMA.
// LDS rows padded 32->40 bf16.
// ---------------------------------------------------------------------------
__global__ __launch_bounds__(256, 2) void gemm_mfma(const float* __restrict__ A, int lda,
                                                    const short* __restrict__ BTh,
                                                    const short* __restrict__ BTm,
                                                    const short* __restrict__ BTl,
                                                    const float* __restrict__ bias,
                                                    float* __restrict__ C, int ldc,
                                                    int qk_cols)
{
    __shared__ __align__(16) short Asm[3][128 * 40];   // [split][m][k] bf16
    __shared__ __align__(16) short Bsm[3][128 * 40];   // [split][n][k] bf16

    const int t       = threadIdx.x;
    const int lane    = t & 63;
    const int wave    = t >> 6;
    const int wr      = wave >> 1;          // wave row half (0/1)
    const int wc      = wave & 1;           // wave col half (0/1)
    const int rowBase = blockIdx.y * 128;
    const int colBase = blockIdx.x * 128;
    const int pstart  = (colBase < qk_cols) ? 0 : 3;   // 6 or 3 products

    // products ordered smallest-magnitude first: lh, hl, mm, mh, hm, hh
    const int sa[6] = {2, 0, 1, 1, 0, 0};
    const int sb[6] = {0, 2, 1, 0, 1, 0};

    const int fn = lane & 15;               // fragment n/m index
    const int fq = (lane >> 4) * 8;         // fragment k offset

    f32x4 acc[4][4] = {};

    for (int ks = 0; ks < 512; ks += 32) {
        __syncthreads();                    // previous tile's readers done

        // ---- stage A: 128x32 fp32, split 3-way, [m][k] bf16 rows ----
#pragma unroll
        for (int lo = 0; lo < 4; ++lo) {
            int idx = lo * 256 + t;         // 0..1023 float4-chunks
            int am  = idx >> 3;             // 0..127
            int af  = (idx & 7) * 4;        // k offset 0..28
            float4 a4 = *(const float4*)&A[(size_t)(rowBase + am) * lda + ks + af];
            Split3 s0 = split3(a4.x);
            Split3 s1 = split3(a4.y);
            Split3 s2 = split3(a4.z);
            Split3 s3 = split3(a4.w);
            s16x4 hv, mv, lv;
            hv[0] = s0.h; hv[1] = s1.h; hv[2] = s2.h; hv[3] = s3.h;
            mv[0] = s0.m; mv[1] = s1.m; mv[2] = s2.m; mv[3] = s3.m;
            lv[0] = s0.l; lv[1] = s1.l; lv[2] = s2.l; lv[3] = s3.l;
            int o = am * 40 + af;
            *(s16x4*)&Asm[0][o] = hv;
            *(s16x4*)&Asm[1][o] = mv;
            *(s16x4*)&Asm[2][o] = lv;
        }
        // ---- stage B: copy pre-split bf16 rows [n][k] (b128 in/out) ----
#pragma unroll
        for (int lo = 0; lo < 2; ++lo) {
            int c = lo * 256 + t;           // 0..511 b128-chunks
            int n = c >> 2;                 // 0..127
            int q = (c & 3) * 8;            // k offset
            size_t src = (size_t)(colBase + n) * 512 + ks + q;
            int o = n * 40 + q;
            *(s16x8*)&Bsm[0][o] = *(const s16x8*)&BTh[src];
            *(s16x8*)&Bsm[1][o] = *(const s16x8*)&BTm[src];
            *(s16x8*)&Bsm[2][o] = *(const s16x8*)&BTl[src];
        }
        __syncthreads();

        // ---- fragments + MFMA ----
        bf16x8 Bf[3][4];
#pragma unroll
        for (int s = 0; s < 3; ++s)
#pragma unroll
            for (int j = 0; j < 4; ++j)
                Bf[s][j] = *(const bf16x8*)&Bsm[s][(wc * 64 + j * 16 + fn) * 40 + fq];

#pragma unroll
        for (int i = 0; i < 4; ++i) {
            bf16x8 Af[3];
#pragma unroll
            for (int s = 0; s < 3; ++s)
                Af[s] = *(const bf16x8*)&Asm[s][(wr * 64 + i * 16 + fn) * 40 + fq];
#pragma unroll
            for (int p = 0; p < 6; ++p) {
                if (p < pstart) continue;   // block-uniform product count
#pragma unroll
                for (int j = 0; j < 4; ++j)
                    acc[i][j] = __builtin_amdgcn_mfma_f32_16x16x32_bf16(
                        Af[sa[p]], Bf[sb[p]][j], acc[i][j], 0, 0, 0);
            }
        }
    }

    // ---- epilogue: C/D layout col=lane&15, row=(lane>>4)*4+reg ----
    const int crow0 = rowBase + wr * 64 + (lane >> 4) * 4;
    const int ccol0 = colBase + wc * 64 + fn;
#pragma unroll
    for (int j = 0; j < 4; ++j) {
        int col = ccol0 + j * 16;
        float bv = bias ? bias[col] : 0.0f;
#pragma unroll
        for (int i = 0; i < 4; ++i)
#pragma unroll
            for (int r = 0; r < 4; ++r)
                C[(size_t)(crow0 + i * 16 + r) * ldc + col] = acc[i][j][r] + bv;
    }
}

// ---------------------------------------------------------------------------
__global__ __launch_bounds__(256) void means_kernel(const float* __restrict__ qkv,
                                                    float* __restrict__ q_mean,
                                                    float* __restrict__ k_mean)
{
    int idx = blockIdx.x * 256 + threadIdx.x;    // 0 .. 524287
    int dd = idx & 63;
    int i  = (idx >> 6) & 255;
    int bh = idx >> 14;                          // 0..31
    int b = bh >> 3, h = bh & 7;
    const float* base = qkv + (size_t)b * NN * 1536 + (size_t)h * 64 + dd;
    float qs = 0.f, ks = 0.f;
#pragma unroll
    for (int w = 0; w < 32; ++w) {
        size_t off = (size_t)(w * 256 + i) * 1536;
        qs += base[off];
        ks += base[off + 512];
    }
    q_mean[idx] = qs * 0.03125f;
    k_mean[idx] = ks * 0.03125f;
}

// ---------------------------------------------------------------------------
__global__ __launch_bounds__(256) void globalbias_kernel(const float* __restrict__ q_mean,
                                                         const float* __restrict__ k_mean,
                                                         const float* __restrict__ gp,
                                                         float* __restrict__ gbias)
{
    __shared__ float gq[32 * 64];    // gq[g][dd]
    const int bh = blockIdx.x;
    const int h  = bh & 7;
    const int t  = threadIdx.x;

#pragma unroll
    for (int e = 0; e < 8; ++e) {
        int idx = e * 256 + t;       // 0..2047
        int g  = idx >> 6;
        int dd = idx & 63;
        const float* gpr = gp + (size_t)(h * 32 + g) * 256;
        const float* qm  = q_mean + (size_t)bh * 16384 + dd;
        float s = 0.f;
        for (int i = 0; i < 256; ++i) s += gpr[i] * qm[(size_t)i * 64];
        gq[idx] = s;
    }
    __syncthreads();

    const float* km = k_mean + (size_t)bh * 16384 + (size_t)t * 64;
    float4 kr[16];
#pragma unroll
    for (int j = 0; j < 16; ++j) kr[j] = *(const float4*)&km[4 * j];
    float acc = 0.f;
    for (int g = 0; g < 32; ++g) {
        const float* gqr = &gq[g * 64];
        float s = 0.f;
#pragma unroll
        for (int j = 0; j < 16; ++j) {
            float4 q4 = *(const float4*)&gqr[4 * j];
            s += q4.x * kr[j].x + q4.y * kr[j].y + q4.z * kr[j].z + q4.w * kr[j].w;
        }
        acc += s;
    }
    gbias[bh * 256 + t] = acc * SCALE * 0.03125f;
}

// ---------------------------------------------------------------------------
// monotone fp32 <-> uint encoding (order-preserving)
__device__ __forceinline__ unsigned mono_enc(float f) {
    unsigned u = __float_as_uint(f);
    return (u & 0x80000000u) ? ~u : (u | 0x80000000u);
}
__device__ __forceinline__ float mono_dec(unsigned e) {
    return (e & 0x80000000u) ? __uint_as_float(e ^ 0x80000000u)
                             : __uint_as_float(~e);
}

// ---------------------------------------------------------------------------
// Fused windowed attention, one block per (b,h,w,rc): 64 rows x 256 cols.
// (unchanged from round 3)
// ---------------------------------------------------------------------------
__global__ __launch_bounds__(256, 3) void attn_kernel(float* __restrict__ qkv,
                                                      const float* __restrict__ local_bias,
                                                      const float* __restrict__ gbias,
                                                      const float* __restrict__ gate)
{
    __shared__ float qT[64 * 68];   // qT[d][(r+d&60)&63]  swizzled transpose
    __shared__ float kT[64 * 68];   // kT[d][(m+d&60)&63] in S phase; v[m][dd] in PV
    __shared__ float st[64 * 68];   // S tile [r][m']; p^T [m][r] in PV

    const int t   = threadIdx.x;
    const int blk = blockIdx.x;            // (((b*8+h)*32 + w)*4 + rc)
    const int rc  = blk & 3;
    const int w   = (blk >> 2) & 31;
    const int bh  = blk >> 7;
    const int h   = bh & 7;
    const int b   = bh >> 3;
    const float gateh = 1.0f / (1.0f + __expf(-gate[h]));

    const size_t tokBase = (size_t)b * NN + (size_t)w * WSZ;
    float* qb = qkv + tokBase * 1536 + h * 64;
    const float* kb = qb + 512;
    const float* vb = qb + 1024;

    const int tr = t >> 4, tc = t & 15;    // tile compute mapping (4x4 / thread)
    const int rr = t >> 2, sub = t & 3;    // row-ownership mapping (4 thr / row)

#pragma unroll
    for (int l = 0; l < 4; ++l) {
        int f  = l * 256 + t;
        int r  = f >> 4;
        int dg = (f & 15) * 4;
        float4 v4 = *(const float4*)&qb[(size_t)(rc * 64 + r) * 1536 + dg];
        int cs = (r + dg) & 63;
        qT[(dg + 0) * 68 + cs] = v4.x;
        qT[(dg + 1) * 68 + cs] = v4.y;
        qT[(dg + 2) * 68 + cs] = v4.z;
        qT[(dg + 3) * 68 + cs] = v4.w;
    }

    float vals[64];
#pragma unroll
    for (int mc = 0; mc < 4; ++mc) {
        __syncthreads();
#pragma unroll
        for (int l = 0; l < 4; ++l) {
            int f  = l * 256 + t;
            int m  = f >> 4;
            int dg = (f & 15) * 4;
            float4 v4 = *(const float4*)&kb[(size_t)(mc * 64 + m) * 1536 + dg];
            int cs = (m + dg) & 63;
            kT[(dg + 0) * 68 + cs] = v4.x;
            kT[(dg + 1) * 68 + cs] = v4.y;
            kT[(dg + 2) * 68 + cs] = v4.z;
            kT[(dg + 3) * 68 + cs] = v4.w;
        }
        __syncthreads();

        float acc[4][4] = {};
#pragma unroll 8
        for (int d = 0; d < 64; ++d) {
            int sw = d & 60;
            float4 q4 = *(const float4*)&qT[d * 68 + ((4 * tr + sw) & 63)];
            float4 k4 = *(const float4*)&kT[d * 68 + ((4 * tc + sw) & 63)];
            float qa[4] = {q4.x, q4.y, q4.z, q4.w};
            float ka[4] = {k4.x, k4.y, k4.z, k4.w};
#pragma unroll
            for (int i = 0; i < 4; ++i)
#pragma unroll
                for (int j = 0; j < 4; ++j)
                    acc[i][j] += qa[i] * ka[j];
        }
        float4 gb4 = *(const float4*)&gbias[bh * 256 + mc * 64 + 4 * tc];
        float gbl[4] = {gb4.x, gb4.y, gb4.z, gb4.w};
#pragma unroll
        for (int i = 0; i < 4; ++i) {
            int row = rc * 64 + 4 * tr + i;
            float4 lb4 = *(const float4*)&local_bias[((size_t)h * 256 + row) * 256 + mc * 64 + 4 * tc];
            float4 o;
            o.x = acc[i][0] * SCALE + lb4.x + gateh * gbl[0];
            o.y = acc[i][1] * SCALE + lb4.y + gateh * gbl[1];
            o.z = acc[i][2] * SCALE + lb4.z + gateh * gbl[2];
            o.w = acc[i][3] * SCALE + lb4.w + gateh * gbl[3];
            *(float4*)&st[(4 * tr + i) * 68 + 4 * tc] = o;
        }
        __syncthreads();
#pragma unroll
        for (int j = 0; j < 16; ++j)
            vals[mc * 16 + j] = st[rr * 68 + sub + 4 * j];
    }

    // ---- top-KKEEP threshold ----
    float rmin = vals[0], rmax = vals[0];
#pragma unroll
    for (int j = 1; j < 64; ++j) {
        rmin = fminf(rmin, vals[j]);
        rmax = fmaxf(rmax, vals[j]);
    }
    rmin = fminf(rmin, __shfl_xor(rmin, 1)); rmin = fminf(rmin, __shfl_xor(rmin, 2));
    rmax = fmaxf(rmax, __shfl_xor(rmax, 1)); rmax = fmaxf(rmax, __shfl_xor(rmax, 2));

    float flo = rmin, fhi = rmax;
    float thr = 0.f;
    bool  done = false;
    for (int it = 0; it < 16; ++it) {
        if (__all(done ? 1 : 0)) break;
        float mf = 0.5f * (flo + fhi);
        int c = 0;
#pragma unroll
        for (int j = 0; j < 64; ++j) c += (vals[j] >= mf) ? 1 : 0;
        c += __shfl_xor(c, 1);
        c += __shfl_xor(c, 2);
        if (!done) {
            if (c == KKEEP)      { thr = mf; done = true; }
            else if (c > KKEEP)  flo = mf;
            else                 fhi = mf;
        }
    }
    if (__any(done ? 0 : 1)) {
        unsigned lo_u = mono_enc(flo), hi_u = mono_enc(fhi);
        for (int it = 0; it < 34; ++it) {
            bool active = (!done) && (lo_u < hi_u);
            if (!__any(active ? 1 : 0)) break;
            unsigned span = hi_u - lo_u;
            unsigned mid  = lo_u + (span >> 1) + (span & 1u);
            float mf = mono_dec(mid);
            int c = 0;
#pragma unroll
            for (int j = 0; j < 64; ++j) c += (vals[j] >= mf) ? 1 : 0;
            c += __shfl_xor(c, 1);
            c += __shfl_xor(c, 2);
            if (active) {
                if (c == KKEEP)      { thr = mf; done = true; }
                else if (c >= KKEEP) lo_u = mid;
                else                 hi_u = mid - 1;
            }
        }
        if (!done) thr = mono_dec(lo_u);
    }

    // ---- masked softmax ----
    float rmx = -3e38f;
#pragma unroll
    for (int j = 0; j < 64; ++j) rmx = fmaxf(rmx, (vals[j] >= thr) ? vals[j] : -3e38f);
    rmx = fmaxf(rmx, __shfl_xor(rmx, 1));
    rmx = fmaxf(rmx, __shfl_xor(rmx, 2));
    float rsum = 0.f;
#pragma unroll
    for (int j = 0; j < 64; ++j) {
        float e = (vals[j] >= thr) ? __expf(vals[j] - rmx) : 0.f;
        vals[j] = e;
        rsum += e;
    }
    rsum += __shfl_xor(rsum, 1);
    rsum += __shfl_xor(rsum, 2);
    float rinv = 1.0f / rsum;
#pragma unroll
    for (int j = 0; j < 64; ++j) vals[j] *= rinv;

    // ---- PV as register-tile GEMM ----
    float acc2[4][4] = {};
#pragma unroll
    for (int mc = 0; mc < 4; ++mc) {
        __syncthreads();
#pragma unroll
        for (int j = 0; j < 16; ++j)
            st[(sub + 4 * j) * 68 + rr] = vals[mc * 16 + j];
#pragma unroll
        for (int l = 0; l < 4; ++l) {
            int f  = l * 256 + t;
            int m  = f >> 4;
            int dg = (f & 15) * 4;
            *(float4*)&kT[m * 68 + dg] =
                *(const float4*)&vb[(size_t)(mc * 64 + m) * 1536 + dg];
        }
        __syncthreads();
#pragma unroll 8
        for (int m = 0; m < 64; ++m) {
            float4 p4 = *(const float4*)&st[m * 68 + 4 * tr];
            float4 v4 = *(const float4*)&kT[m * 68 + 4 * tc];
            float pa[4] = {p4.x, p4.y, p4.z, p4.w};
            float va[4] = {v4.x, v4.y, v4.z, v4.w};
#pragma unroll
            for (int i = 0; i < 4; ++i)
#pragma unroll
                for (int j = 0; j < 4; ++j)
                    acc2[i][j] += pa[i] * va[j];
        }
    }

#pragma unroll
    for (int i = 0; i < 4; ++i) {
        float4 o;
        o.x = acc2[i][0]; o.y = acc2[i][1]; o.z = acc2[i][2]; o.w = acc2[i][3];
        *(float4*)&qb[(size_t)(rc * 64 + 4 * tr + i) * 1536 + 4 * tc] = o;
    }
}

// ---------------------------------------------------------------------------
extern "C" void kernel_launch(void* const* d_in, const int* in_sizes, int n_in,
                              void* d_out, int out_size, void* d_ws, size_t ws_size,
                              hipStream_t stream)
{
    (void)in_sizes; (void)n_in; (void)out_size; (void)ws_size;
    const float* x            = (const float*)d_in[0];
    const float* w_qkv        = (const float*)d_in[1];
    const float* w_out        = (const float*)d_in[2];
    const float* b_out        = (const float*)d_in[3];
    const float* local_bias   = (const float*)d_in[4];
    const float* global_param = (const float*)d_in[5];
    const float* gate         = (const float*)d_in[6];
    float* out = (float*)d_out;
    float* ws  = (float*)d_ws;

    // ws layout: qkv(192MB) | q_mean | k_mean | gbias | bf16 weight splits (~6MB)
    float* qkv    = ws;                                   // 32768*1536 f32
    float* q_mean = qkv + (size_t)32768 * 1536;           // 32*256*64
    float* k_mean = q_mean + (size_t)32 * 256 * 64;
    float* gb     = k_mean + (size_t)32 * 256 * 64;       // 32*256
    short* wsp    = (short*)(gb + 8192);
    short* WTh  = wsp;                    // w_qkv^T splits: [1536][512] bf16
    short* WTm  = WTh + (size_t)1536 * 512;
    short* WTl  = WTm + (size_t)1536 * 512;
    short* WoTh = WTl + (size_t)1536 * 512;   // w_out^T splits: [512][512]
    short* WoTm = WoTh + (size_t)512 * 512;
    short* WoTl = WoTm + (size_t)512 * 512;

    // 0) pre-split + transpose weights to bf16 limbs
    splitw_kernel<<<3072, 256, 0, stream>>>(w_qkv, 512, 1536, WTh, WTm, WTl);
    splitw_kernel<<<1024, 256, 0, stream>>>(w_out, 512, 512, WoTh, WoTm, WoTl);
    // 1) QKV projection via MFMA (6 limb-products for q/k cols, 3 for v cols)
    gemm_mfma<<<dim3(12, 256), 256, 0, stream>>>(x, 512, WTh, WTm, WTl,
                                                 nullptr, qkv, 1536, 1024);
    // 2) window means of q and k
    means_kernel<<<2048, 256, 0, stream>>>(qkv, q_mean, k_mean);
    // 3) global bias per (b,h,m)
    globalbias_kernel<<<32, 256, 0, stream>>>(q_mean, k_mean, global_param, gb);
    // 4) fused windowed attention; output in-place into q-slice of qkv
    attn_kernel<<<4096, 256, 0, stream>>>(qkv, local_bias, gb, gate);
    // 5) output projection via MFMA (3 limb-products) + bias
    gemm_mfma<<<dim3(4, 256), 256, 0, stream>>>(qkv, 1536, WoTh, WoTm, WoTl,
                                                b_out, out, 512, 0);
}